// Round 5
// baseline (223.030 us; speedup 1.0000x reference)
//
#include <hip/hip_runtime.h>

// ---------------------------------------------------------------------------
// SelfAttention, L=2048, E=1024, H=16, D=64. fp32 in/out, bf16 MFMA compute.
//   cvt_all     : f32->bf16 (q,k,v,W*) + bias = (1/(1+dist))*log2e/32 as bf16
//   bias_fill   : out[q][:] = bo (out-proj accumulates on top via atomics)
//   gemm_bt3c<0>: Q,K,V projections (z selects tensor; z=2 writes V^T)
//   flash3      : split-K flash, S^T-form softmax (packed P writes), no-max
//   merge_attn  : sum partials, divide, write bf16 AO
//   gemm_bt3c<2>: out += AO @ Wo^T, split-K=4 over z, unsafeAtomicAdd f32
// GEMM core: BK=64 (32 MFMA/barrier), global_load_lds staging with XOR-swizzled
// LDS granules (conflict-free b128 frag reads, no padding needed).
// ---------------------------------------------------------------------------

#define L_SEQ 2048
#define E_DIM 1024
#define H_HEADS 16
#define D_HEAD 64
#define KSPLIT 4

typedef unsigned short u16;
typedef unsigned int u32;
typedef __attribute__((ext_vector_type(8))) short bf16x8;
typedef __attribute__((ext_vector_type(8))) unsigned short u16x8;
typedef __attribute__((ext_vector_type(4))) unsigned short u16x4;
typedef __attribute__((ext_vector_type(4))) float f32x4;

#define C_LOG2E_32 0.045084220027780106f   // log2(e)/32

__device__ __forceinline__ float bf2f(u16 u) {
  union { u32 i; float f; } v; v.i = ((u32)u) << 16; return v.f;
}
__device__ __forceinline__ u16 f2bf(float f) {
  union { float f; u32 i; } v; v.f = f;
  u32 u = v.i;
  u += 0x7FFFu + ((u >> 16) & 1u);   // RNE
  return (u16)(u >> 16);
}
// pack bf16(lo), bf16(hi) into one u32 (round-half-up; operands > 0)
__device__ __forceinline__ u32 pack_bf16_pair(float lo, float hi) {
  union { float f; u32 u; } a, b;
  a.f = lo; b.f = hi;
  return __builtin_amdgcn_perm(b.u + 0x8000u, a.u + 0x8000u, 0x07060302u);
}
// async global->LDS 16B/lane; LDS dest = (wave-uniform base) + lane*16
__device__ __forceinline__ void gload16(const u16* g, u16* l) {
  __builtin_amdgcn_global_load_lds(
      (const __attribute__((address_space(1))) u32*)g,
      (__attribute__((address_space(3))) u32*)l, 16, 0, 0);
}

// ---------------------------------------------------------------------------
// One-shot conversion: inputs+weights f32->bf16; bias prescaled by log2e/32.
// ---------------------------------------------------------------------------
__global__ void cvt_all(const float* __restrict__ xq, const float* __restrict__ xk,
                        const float* __restrict__ xv,
                        const float* __restrict__ wq, const float* __restrict__ wk,
                        const float* __restrict__ wv, const float* __restrict__ wo,
                        const float* __restrict__ dist,
                        u16* oq, u16* ok, u16* ov,
                        u16* owq, u16* owk, u16* owv, u16* owo, u16* obias)
{
  size_t gid = (size_t)blockIdx.x * 256 + threadIdx.x;   // one f32x4 per thread
  const size_t NQ = 524288;   // (L*E)/4
  const size_t NW = 262144;   // (E*E)/4
  const float* src; u16* dst; size_t off; bool isb = false;
  if      (gid <     NQ)           { src = xq;   dst = oq;    off = gid; }
  else if (gid < 2 * NQ)           { src = xk;   dst = ok;    off = gid - NQ; }
  else if (gid < 3 * NQ)           { src = xv;   dst = ov;    off = gid - 2 * NQ; }
  else if (gid < 3 * NQ + NW)      { src = wq;   dst = owq;   off = gid - 3 * NQ; }
  else if (gid < 3 * NQ + 2 * NW)  { src = wk;   dst = owk;   off = gid - 3 * NQ - NW; }
  else if (gid < 3 * NQ + 3 * NW)  { src = wv;   dst = owv;   off = gid - 3 * NQ - 2 * NW; }
  else if (gid < 3 * NQ + 4 * NW)  { src = wo;   dst = owo;   off = gid - 3 * NQ - 3 * NW; }
  else { src = dist; dst = obias; off = gid - 3 * NQ - 4 * NW; isb = true; }

  f32x4 v = *(const f32x4*)&src[off * 4];
  u16x4 o;
#pragma unroll
  for (int j = 0; j < 4; ++j) {
    float f = v[j];
    if (isb) f = (f == 0.f) ? 0.f : C_LOG2E_32 / (f + 1.f);
    o[j] = f2bf(f);
  }
  *(u16x4*)&dst[off * 4] = o;
}

// out[q][n] = bo[n]  (the out-proj GEMM atomically accumulates on top)
__global__ void bias_fill(const float* __restrict__ bo, float* __restrict__ out)
{
  size_t gid = (size_t)blockIdx.x * 256 + threadIdx.x;
  int n = (int)((gid * 4) & (E_DIM - 1));
  *(f32x4*)&out[gid * 4] = *(const f32x4*)&bo[n];
}

// ---------------------------------------------------------------------------
// NT GEMM, bf16: C[M,N] = A[M,K]*B[N,K]^T. 128x128 tile, BK=64, 4 waves.
// global_load_lds staging; LDS granule (16B) at [row][g] holds global granule
// g^(row&7) -> fragment reads hit all banks (2-way = free).
// OUTMODE 0: triple (z selects A/B/C), bf16 out, z==2 writes C^T.
// OUTMODE 2: single tensor, z = K-split (K/KSPLIT each), f32 atomic-add out.
// ---------------------------------------------------------------------------
#define TM 128
#define TN 128
#define BK 64

template<int OUTMODE>
__global__ __launch_bounds__(256, 2) void gemm_bt3c(
    const u16* __restrict__ A0, const u16* __restrict__ B0, void* __restrict__ C0,
    const u16* __restrict__ A1, const u16* __restrict__ B1, void* __restrict__ C1,
    const u16* __restrict__ A2, const u16* __restrict__ B2, void* __restrict__ C2,
    int M, int N, int K)
{
  const u16* A; const u16* B; void* C;
  if (OUTMODE == 2)         { A = A0; B = B0; C = C0; }
  else if (blockIdx.z == 0) { A = A0; B = B0; C = C0; }
  else if (blockIdx.z == 1) { A = A1; B = B1; C = C1; }
  else                      { A = A2; B = B2; C = C2; }

  __shared__ __align__(16) u16 As[TM * BK];   // 16 KB, swizzled granules
  __shared__ __align__(16) u16 Bs[TN * BK];   // 16 KB

  const int m0 = blockIdx.y * TM;
  const int n0 = blockIdx.x * TN;
  const int t = threadIdx.x;
  const int wave = t >> 6;
  const int lane = t & 63;
  const int quad = lane >> 4;
  const int col  = lane & 15;
  const int wm = (wave >> 1) * 64;
  const int wn = (wave & 1) * 64;

  // staging: one gload16 covers 8 rows x 64 cols; lane -> row lane/8,
  // LDS slot lane&7, global granule (lane&7)^(lane/8)  (rbase is mult of 8)
  const int roff = lane >> 3;
  const int gcol = ((lane & 7) ^ roff) * 8;
  const u16* gA = A + (size_t)(m0 + wave * 32 + roff) * K + gcol;
  const u16* gB = B + (size_t)(n0 + wave * 32 + roff) * K + gcol;

  const int kbeg = (OUTMODE == 2) ? blockIdx.z * (K / KSPLIT) : 0;
  const int kend = (OUTMODE == 2) ? kbeg + K / KSPLIT : K;

  f32x4 acc[4][4];
#pragma unroll
  for (int i = 0; i < 4; ++i)
#pragma unroll
    for (int j = 0; j < 4; ++j) acc[i][j] = (f32x4){0.f, 0.f, 0.f, 0.f};

  // fragment LDS offsets (u16 elems): row*64 + slot*8, slot = (ks*4+quad)^(col&7)
  const int c7 = col & 7;

  for (int k0 = kbeg; k0 < kend; k0 += BK) {
    __syncthreads();
#pragma unroll
    for (int s = 0; s < 4; ++s) {
      gload16(gA + (size_t)(s * 8) * K + k0, &As[(wave * 32 + s * 8) * BK]);
      gload16(gB + (size_t)(s * 8) * K + k0, &Bs[(wave * 32 + s * 8) * BK]);
    }
    __syncthreads();   // vmcnt drained -> LDS visible

    bf16x8 af[4][2], bfr[4][2];
#pragma unroll
    for (int ks = 0; ks < 2; ++ks) {
      const int slot = ((ks * 4 + quad) ^ c7) * 8;
#pragma unroll
      for (int i = 0; i < 4; ++i)
        af[i][ks] = *(const bf16x8*)&As[(wm + i * 16 + col) * BK + slot];
#pragma unroll
      for (int j = 0; j < 4; ++j)
        bfr[j][ks] = *(const bf16x8*)&Bs[(wn + j * 16 + col) * BK + slot];
    }

#pragma unroll
    for (int ks = 0; ks < 2; ++ks)
#pragma unroll
      for (int i = 0; i < 4; ++i)
#pragma unroll
        for (int j = 0; j < 4; ++j)
          acc[i][j] = __builtin_amdgcn_mfma_f32_16x16x32_bf16(af[i][ks], bfr[j][ks], acc[i][j], 0, 0, 0);
  }

  const bool transC = (OUTMODE == 0) && (blockIdx.z == 2);
#pragma unroll
  for (int i = 0; i < 4; ++i) {
    int rowb = m0 + wm + i * 16 + quad * 4;
#pragma unroll
    for (int j = 0; j < 4; ++j) {
      int cn = n0 + wn + j * 16 + col;
      if (OUTMODE == 2) {
#pragma unroll
        for (int r = 0; r < 4; ++r)
          unsafeAtomicAdd(&((float*)C)[(size_t)(rowb + r) * N + cn], acc[i][j][r]);
      } else if (transC) {
        u16x4 pk;
#pragma unroll
        for (int r = 0; r < 4; ++r) pk[r] = f2bf(acc[i][j][r]);
        *(u16x4*)&((u16*)C)[(size_t)cn * M + rowb] = pk;   // C^T: 4 contiguous
      } else {
#pragma unroll
        for (int r = 0; r < 4; ++r)
          ((u16*)C)[(size_t)(rowb + r) * N + cn] = f2bf(acc[i][j][r]);
      }
    }
  }
}

// ---------------------------------------------------------------------------
// Split-K flash attention, S^T form (see round 4). Partial O (bf16) + l (f32).
// ---------------------------------------------------------------------------
#define FK 64
#define LDV 72   // +8 pad, 144B rows (16B-aligned)

__global__ __launch_bounds__(256, 5) void flash3(
    const u16* __restrict__ Q, const u16* __restrict__ Kp,
    const u16* __restrict__ Vt, const u16* __restrict__ Bb,
    u16* __restrict__ Op, float* __restrict__ lp)
{
  __shared__ __align__(16) u16 Ks[FK][LDV];      // K-tile [l][d]
  __shared__ __align__(16) u16 Vs[D_HEAD][LDV];  // V^T tile [d][l]
  __shared__ __align__(16) u16 Ps[4][16][LDV];   // per-wave P strip [q-row][l]

  const int h  = blockIdx.y;
  const int q0 = blockIdx.x * 64;
  const int z  = blockIdx.z;
  const int hoff = h * D_HEAD;
  const int kbase = z * (L_SEQ / KSPLIT);
  const int t = threadIdx.x;
  const int wave = t >> 6;
  const int lane = t & 63;
  const int quad = lane >> 4;
  const int col  = lane & 15;

  // Q fragments (B-operand: n = q = col, k = d = quad*8+j)
  bf16x8 qf[2];
  {
    const u16* qrow = Q + (size_t)(q0 + wave * 16 + col) * E_DIM + hoff;
    qf[0] = *(const bf16x8*)(qrow + quad * 8);
    qf[1] = *(const bf16x8*)(qrow + 32 + quad * 8);
  }

  float l_lane = 0.f;                 // partial row-sum for q = q0+wave*16+col
  f32x4 oacc[4];
#pragma unroll
  for (int td = 0; td < 4; ++td) oacc[td] = (f32x4){0.f, 0.f, 0.f, 0.f};

  const u16* brow = Bb + (size_t)(q0 + wave * 16 + col) * L_SEQ;  // prescaled bias
  const int cst = t & 7, rst = t >> 3;

  for (int kt = 0; kt < L_SEQ / KSPLIT / FK; ++kt) {
    const int k0 = kbase + kt * FK;
    __syncthreads();
#pragma unroll
    for (int s = 0; s < 2; ++s) {
      int rr = rst + s * 32;
      *(u16x8*)&Ks[rr][cst * 8] = *(const u16x8*)&Kp[(size_t)(k0 + rr) * E_DIM + hoff + cst * 8];
      *(u16x8*)&Vs[rr][cst * 8] = *(const u16x8*)&Vt[(size_t)(hoff + rr) * L_SEQ + k0 + cst * 8];
    }
    // bias (prescaled): lane needs l = tt*16+quad*4..+3 for its q -> 8B loads
    float pb[4][4];
#pragma unroll
    for (int tt = 0; tt < 4; ++tt) {
      u16x4 bv = *(const u16x4*)&brow[k0 + tt * 16 + quad * 4];
#pragma unroll
      for (int r = 0; r < 4; ++r) pb[tt][r] = bf2f(bv[r]);
    }
    __syncthreads();

    // S^T = K Q^T : A = K-frag (m=l), B = Q-frag (n=q). C/D: col=q, row=l.
#pragma unroll
    for (int tt = 0; tt < 4; ++tt) {
      f32x4 a = (f32x4){0.f, 0.f, 0.f, 0.f};
      a = __builtin_amdgcn_mfma_f32_16x16x32_bf16(*(const bf16x8*)&Ks[tt * 16 + col][quad * 8], qf[0], a, 0, 0, 0);
      a = __builtin_amdgcn_mfma_f32_16x16x32_bf16(*(const bf16x8*)&Ks[tt * 16 + col][32 + quad * 8], qf[1], a, 0, 0, 0);
      float p[4];
#pragma unroll
      for (int r = 0; r < 4; ++r) {
        p[r] = __builtin_amdgcn_exp2f(fmaf(a[r], C_LOG2E_32, pb[tt][r]));
        l_lane += p[r];
      }
      uint2 w;
      w.x = pack_bf16_pair(p[0], p[1]);
      w.y = pack_bf16_pair(p[2], p[3]);
      *(uint2*)&Ps[wave][col][tt * 16 + quad * 4] = w;   // P[q=col][l..l+3]
    }
    // same-wave LDS writes/reads are in-order: no barrier needed for Ps.

    // O += P V : A = P strip [q][l], B = V^T [d][l]
#pragma unroll
    for (int kk = 0; kk < 2; ++kk) {
      bf16x8 pf = *(const bf16x8*)&Ps[wave][col][kk * 32 + quad * 8];
#pragma unroll
      for (int td = 0; td < 4; ++td) {
        bf16x8 vf = *(const bf16x8*)&Vs[td * 16 + col][kk * 32 + quad * 8];
        oacc[td] = __builtin_amdgcn_mfma_f32_16x16x32_bf16(pf, vf, oacc[td], 0, 0, 0);
      }
    }
  }

  l_lane += __shfl_xor(l_lane, 16);
  l_lane += __shfl_xor(l_lane, 32);
  if (lane < 16)
    lp[((size_t)z * L_SEQ + q0 + wave * 16 + lane) * H_HEADS + h] = l_lane;

  const int qrow_mine = q0 + wave * 16 + quad * 4;
#pragma unroll
  for (int td = 0; td < 4; ++td)
#pragma unroll
    for (int r = 0; r < 4; ++r)
      Op[((size_t)z * L_SEQ + qrow_mine + r) * E_DIM + hoff + td * 16 + col] = f2bf(oacc[td][r]);
}

// ---------------------------------------------------------------------------
// Merge split-K partials: AO = (sum_s O_s) / (sum_s l_s), bf16 out.
// ---------------------------------------------------------------------------
__global__ void merge_attn(const u16* __restrict__ Op, const float* __restrict__ lp,
                           u16* __restrict__ AOb)
{
  size_t gid = (size_t)blockIdx.x * 256 + threadIdx.x;
  size_t idx = gid * 4;
  int q = (int)(idx >> 10);
  int e = (int)(idx & 1023);
  int h = e >> 6;
  float o[4] = {0.f, 0.f, 0.f, 0.f};
  float lsum = 0.f;
#pragma unroll
  for (int s = 0; s < KSPLIT; ++s) {
    u16x4 pv = *(const u16x4*)&Op[((size_t)s * L_SEQ + q) * E_DIM + e];
#pragma unroll
    for (int j = 0; j < 4; ++j) o[j] += bf2f(pv[j]);
    lsum += lp[((size_t)s * L_SEQ + q) * H_HEADS + h];
  }
  float inv = 1.f / lsum;
  u16x4 pk;
#pragma unroll
  for (int j = 0; j < 4; ++j) pk[j] = f2bf(o[j] * inv);
  *(u16x4*)&AOb[idx] = pk;
}

// ---------------------------------------------------------------------------
extern "C" void kernel_launch(void* const* d_in, const int* in_sizes, int n_in,
                              void* d_out, int out_size, void* d_ws, size_t ws_size,
                              hipStream_t stream)
{
  const float* values = (const float*)d_in[0];
  const float* keys   = (const float*)d_in[1];
  const float* query  = (const float*)d_in[2];
  const float* dist   = (const float*)d_in[3];
  const float* Wv     = (const float*)d_in[4];
  const float* Wk     = (const float*)d_in[5];
  const float* Wq     = (const float*)d_in[6];
  const float* Wo     = (const float*)d_in[7];
  const float* bo     = (const float*)d_in[8];
  float* out = (float*)d_out;

  const size_t MB = (size_t)1 << 20;
  char* w = (char*)d_ws;
  u16* xq  = (u16*)(w + 0 * MB);    // 4 MB  (dead after proj)
  u16* xk  = (u16*)(w + 4 * MB);    // 4 MB  (dead after proj)
  u16* xv  = (u16*)(w + 8 * MB);    // 4 MB  (dead after proj)
  u16* wqb = (u16*)(w + 12 * MB);   // 2 MB  (dead after proj)
  u16* wkb = (u16*)(w + 14 * MB);   // 2 MB  (dead after proj)
  u16* wvb = (u16*)(w + 16 * MB);   // 2 MB  (dead after proj)
  u16* wob = (u16*)(w + 18 * MB);   // 2 MB  (live to end)
  u16* Bb  = (u16*)(w + 20 * MB);   // 8 MB  prescaled bias bf16 [L][L]
  u16* Qh  = (u16*)(w + 28 * MB);   // 4 MB
  u16* Kh  = (u16*)(w + 32 * MB);   // 4 MB
  u16* Vth = (u16*)(w + 36 * MB);   // 4 MB  V^T [E][L]
  u16* AOb = (u16*)(w + 40 * MB);   // 4 MB
  float* lp = (float*)(w + 44 * MB);// 0.5 MB
  u16* Op  = (u16*)(w + 0 * MB);    // 16 MB, overlaps dead xq..wvb region

  cvt_all<<<14336, 256, 0, stream>>>(query, keys, values, Wq, Wk, Wv, Wo, dist,
                                     xq, xk, xv, wqb, wkb, wvb, wob, Bb);

  bias_fill<<<(L_SEQ * E_DIM / 4) / 256, 256, 0, stream>>>(bo, out);

  dim3 gProj(E_DIM / TN, L_SEQ / TM, 3);
  gemm_bt3c<0><<<gProj, 256, 0, stream>>>(xq, wqb, Qh,
                                          xk, wkb, Kh,
                                          xv, wvb, Vth,
                                          L_SEQ, E_DIM, E_DIM);

  dim3 gAttn(L_SEQ / 64, H_HEADS, KSPLIT);
  flash3<<<gAttn, 256, 0, stream>>>(Qh, Kh, Vth, Bb, Op, lp);

  merge_attn<<<(L_SEQ * E_DIM / 4) / 256, 256, 0, stream>>>(Op, lp, AOb);

  // out += AO @ Wo^T, split-K=4 (512 blocks), atomic f32 accumulate
  dim3 gOut(E_DIM / TN, L_SEQ / TM, KSPLIT);
  gemm_bt3c<2><<<gOut, 256, 0, stream>>>(AOb, wob, out,
                                         AOb, wob, out,
                                         AOb, wob, out,
                                         L_SEQ, E_DIM, E_DIM);
}

// Round 6
// 221.843 us; speedup vs baseline: 1.0054x; 1.0054x over previous
//
#include <hip/hip_runtime.h>

// ---------------------------------------------------------------------------
// SelfAttention, L=2048, E=1024, H=16, D=64. fp32 in/out, bf16 MFMA compute.
//   cvt_all  : f32->bf16 (q,k,v,W*) + bias=(1/(1+dist))*log2e/32 bf16 + out=bo
//   gemm_pd<0>: Q,K,V projections (z selects tensor; z=2 writes V^T)
//   flash4   : split-K flash, S^T softmax; PV^T via mfma 16x16x16 (no P LDS trip)
//   merge_attn: sum partials, divide, write bf16 AO
//   gemm_pd<2>: out += AO @ Wo^T, split-K=2 over z, unsafeAtomicAdd f32
// GEMM core: BK=32 double-buffered LDS, ONE barrier per iter, prefetch issued
// after the barrier so staging loads stay in flight across a full compute
// phase (the m97 barrier-drain fix). XOR-swizzled granules: conflict-free.
// ---------------------------------------------------------------------------

#define L_SEQ 2048
#define E_DIM 1024
#define H_HEADS 16
#define D_HEAD 64
#define KSPLIT 4     // flash k-split
#define OSPLIT 2     // out-proj k-split

typedef unsigned short u16;
typedef unsigned int u32;
typedef __attribute__((ext_vector_type(8))) short bf16x8;
typedef __attribute__((ext_vector_type(4))) short bf16x4;
typedef __attribute__((ext_vector_type(8))) unsigned short u16x8;
typedef __attribute__((ext_vector_type(4))) unsigned short u16x4;
typedef __attribute__((ext_vector_type(4))) float f32x4;

#define C_LOG2E_32 0.045084220027780106f   // log2(e)/32

#if __has_builtin(__builtin_amdgcn_mfma_f32_16x16x16bf16_1k)
#define HAVE_MFMA16 1
#else
#define HAVE_MFMA16 0
#endif

__device__ __forceinline__ float bf2f(u16 u) {
  union { u32 i; float f; } v; v.i = ((u32)u) << 16; return v.f;
}
__device__ __forceinline__ u16 f2bf(float f) {
  union { float f; u32 i; } v; v.f = f;
  u32 u = v.i;
  u += 0x7FFFu + ((u >> 16) & 1u);   // RNE
  return (u16)(u >> 16);
}
// pack bf16(lo), bf16(hi) into one u32 (round-half-up; operands > 0)
__device__ __forceinline__ u32 pack_bf16_pair(float lo, float hi) {
  union { float f; u32 u; } a, b;
  a.f = lo; b.f = hi;
  return __builtin_amdgcn_perm(b.u + 0x8000u, a.u + 0x8000u, 0x07060302u);
}
// async global->LDS 16B/lane; LDS dest = (wave-uniform base) + lane*16
__device__ __forceinline__ void gload16(const u16* g, u16* l) {
  __builtin_amdgcn_global_load_lds(
      (const __attribute__((address_space(1))) u32*)g,
      (__attribute__((address_space(3))) u32*)l, 16, 0, 0);
}

// ---------------------------------------------------------------------------
// One-shot conversion + out-buffer bias prefill.
// ---------------------------------------------------------------------------
__global__ void cvt_all(const float* __restrict__ xq, const float* __restrict__ xk,
                        const float* __restrict__ xv,
                        const float* __restrict__ wq, const float* __restrict__ wk,
                        const float* __restrict__ wv, const float* __restrict__ wo,
                        const float* __restrict__ dist, const float* __restrict__ bo,
                        u16* oq, u16* ok, u16* ov,
                        u16* owq, u16* owk, u16* owv, u16* owo, u16* obias,
                        float* __restrict__ outp)
{
  size_t gid = (size_t)blockIdx.x * 256 + threadIdx.x;   // one x4 group
  const size_t NQ = 524288;    // (L*E)/4
  const size_t NW = 262144;    // (E*E)/4
  const size_t DL = 1048576;   // (L*L)/4
  const size_t FILL = 3 * NQ + 4 * NW + DL;

  if (gid >= FILL) {           // out[q][:] = bo (out-proj accumulates on top)
    size_t off = (gid - FILL) * 4;
    int n = (int)(off & (E_DIM - 1));
    *(f32x4*)&outp[off] = *(const f32x4*)&bo[n];
    return;
  }

  const float* src; u16* dst; size_t off; bool isb = false;
  if      (gid <     NQ)           { src = xq;   dst = oq;    off = gid; }
  else if (gid < 2 * NQ)           { src = xk;   dst = ok;    off = gid - NQ; }
  else if (gid < 3 * NQ)           { src = xv;   dst = ov;    off = gid - 2 * NQ; }
  else if (gid < 3 * NQ + NW)      { src = wq;   dst = owq;   off = gid - 3 * NQ; }
  else if (gid < 3 * NQ + 2 * NW)  { src = wk;   dst = owk;   off = gid - 3 * NQ - NW; }
  else if (gid < 3 * NQ + 3 * NW)  { src = wv;   dst = owv;   off = gid - 3 * NQ - 2 * NW; }
  else if (gid < 3 * NQ + 4 * NW)  { src = wo;   dst = owo;   off = gid - 3 * NQ - 3 * NW; }
  else { src = dist; dst = obias; off = gid - 3 * NQ - 4 * NW; isb = true; }

  f32x4 v = *(const f32x4*)&src[off * 4];
  u16x4 o;
#pragma unroll
  for (int j = 0; j < 4; ++j) {
    float f = v[j];
    if (isb) f = (f == 0.f) ? 0.f : C_LOG2E_32 / (f + 1.f);
    o[j] = f2bf(f);
  }
  *(u16x4*)&dst[off * 4] = o;
}

// ---------------------------------------------------------------------------
// NT GEMM, bf16, pipelined: C[M,N] = A[M,K]*B[N,K]^T. 128x128 tile, BK=32,
// double-buffered LDS (32 KB), one barrier/iter, prefetch after barrier.
// LDS[row][slot] holds global granule slot^((row>>1)&3) -> frag b128 conflict-free.
// OUTMODE 0: triple (z selects A/B/C), bf16 out, z==2 writes C^T.
// OUTMODE 2: single tensor, z = K-split (K/OSPLIT each), f32 atomic-add out.
// ---------------------------------------------------------------------------
#define TM 128
#define TN 128
#define BK 32

template<int OUTMODE>
__global__ __launch_bounds__(256, 3) void gemm_pd(
    const u16* __restrict__ A0, const u16* __restrict__ B0, void* __restrict__ C0,
    const u16* __restrict__ A1, const u16* __restrict__ B1, void* __restrict__ C1,
    const u16* __restrict__ A2, const u16* __restrict__ B2, void* __restrict__ C2,
    int M, int N, int K)
{
  const u16* A; const u16* B; void* C;
  if (OUTMODE == 2)         { A = A0; B = B0; C = C0; }
  else if (blockIdx.z == 0) { A = A0; B = B0; C = C0; }
  else if (blockIdx.z == 1) { A = A1; B = B1; C = C1; }
  else                      { A = A2; B = B2; C = C2; }

  __shared__ __align__(16) u16 As[2][TM * BK];   // 8 KB each buf
  __shared__ __align__(16) u16 Bs[2][TN * BK];

  const int m0 = blockIdx.y * TM;
  const int n0 = blockIdx.x * TN;
  const int t = threadIdx.x;
  const int wave = t >> 6;
  const int lane = t & 63;
  const int quad = lane >> 4;
  const int col  = lane & 15;
  const int wm = (wave >> 1) * 64;
  const int wn = (wave & 1) * 64;

  // staging: one gload16 covers 16 rows x 32 cols; lane -> row lane/4,
  // LDS slot lane&3, global granule (lane&3)^((lane>>3)&3)
  const int roff = lane >> 2;
  const int gcol = ((lane & 3) ^ ((lane >> 3) & 3)) * 8;
  const u16* gA = A + (size_t)(m0 + wave * 32 + roff) * K + gcol;
  const u16* gB = B + (size_t)(n0 + wave * 32 + roff) * K + gcol;
  const int lo0 = (wave * 32) * BK;        // LDS offset for s=0 rows
  const int lo1 = (wave * 32 + 16) * BK;   // s=1 rows

  const int kbeg = (OUTMODE == 2) ? blockIdx.z * (K / OSPLIT) : 0;
  const int kend = (OUTMODE == 2) ? kbeg + K / OSPLIT : K;

  f32x4 acc[4][4];
#pragma unroll
  for (int i = 0; i < 4; ++i)
#pragma unroll
    for (int j = 0; j < 4; ++j) acc[i][j] = (f32x4){0.f, 0.f, 0.f, 0.f};

  // prologue: stage first tile into buf 0
  gload16(gA + kbeg, &As[0][lo0]);
  gload16(gA + (size_t)16 * K + kbeg, &As[0][lo1]);
  gload16(gB + kbeg, &Bs[0][lo0]);
  gload16(gB + (size_t)16 * K + kbeg, &Bs[0][lo1]);

  const int slot8 = (quad ^ ((col >> 1) & 3)) * 8;   // frag granule (swizzled)

  int buf = 0;
  for (int k0 = kbeg; k0 < kend; k0 += BK) {
    __syncthreads();   // drains vmcnt: tile(buf) visible; prev iter's reads done
    int nk = k0 + BK;
    if (nk < kend) {   // prefetch next tile into other buf; drains NEXT barrier
      gload16(gA + nk, &As[buf ^ 1][lo0]);
      gload16(gA + (size_t)16 * K + nk, &As[buf ^ 1][lo1]);
      gload16(gB + nk, &Bs[buf ^ 1][lo0]);
      gload16(gB + (size_t)16 * K + nk, &Bs[buf ^ 1][lo1]);
    }

    bf16x8 af[4], bfr[4];
#pragma unroll
    for (int i = 0; i < 4; ++i)
      af[i] = *(const bf16x8*)&As[buf][(wm + i * 16 + col) * BK + slot8];
#pragma unroll
    for (int j = 0; j < 4; ++j)
      bfr[j] = *(const bf16x8*)&Bs[buf][(wn + j * 16 + col) * BK + slot8];

#pragma unroll
    for (int i = 0; i < 4; ++i)
#pragma unroll
      for (int j = 0; j < 4; ++j)
        acc[i][j] = __builtin_amdgcn_mfma_f32_16x16x32_bf16(af[i], bfr[j], acc[i][j], 0, 0, 0);

    buf ^= 1;
  }

  const bool transC = (OUTMODE == 0) && (blockIdx.z == 2);
#pragma unroll
  for (int i = 0; i < 4; ++i) {
    int rowb = m0 + wm + i * 16 + quad * 4;
#pragma unroll
    for (int j = 0; j < 4; ++j) {
      int cn = n0 + wn + j * 16 + col;
      if (OUTMODE == 2) {
#pragma unroll
        for (int r = 0; r < 4; ++r)
          unsafeAtomicAdd(&((float*)C)[(size_t)(rowb + r) * N + cn], acc[i][j][r]);
      } else if (transC) {
        u16x4 pk;
#pragma unroll
        for (int r = 0; r < 4; ++r) pk[r] = f2bf(acc[i][j][r]);
        *(u16x4*)&((u16*)C)[(size_t)cn * M + rowb] = pk;   // C^T: 4 contiguous
      } else {
#pragma unroll
        for (int r = 0; r < 4; ++r)
          ((u16*)C)[(size_t)(rowb + r) * N + cn] = f2bf(acc[i][j][r]);
      }
    }
  }
}

// ---------------------------------------------------------------------------
// Split-K flash attention, S^T form. PV^T computed with mfma 16x16x16:
// S^T C/D layout (q=col, l=quad*4+r) IS the 16x16x16 B-operand layout
// (n=col, k=quad*4+j) -> P goes acc -> pack -> MFMA, no LDS round-trip.
// O^T accumulates (d=quad*4+r, q=col); partial O (bf16) + l (f32) per split.
// ---------------------------------------------------------------------------
#define FK 64
#define LDV 72   // +8 pad, 144B rows (16B-aligned)

__global__ __launch_bounds__(256, 6) void flash4(
    const u16* __restrict__ Q, const u16* __restrict__ Kp,
    const u16* __restrict__ Vt, const u16* __restrict__ Bb,
    u16* __restrict__ Op, float* __restrict__ lp)
{
  __shared__ __align__(16) u16 Ks[FK][LDV];      // K-tile [l][d]
  __shared__ __align__(16) u16 Vs[D_HEAD][LDV];  // V^T tile [d][l]
#if !HAVE_MFMA16
  __shared__ __align__(16) u16 Ps[4][16][LDV];   // fallback P strip
#endif

  const int h  = blockIdx.y;
  const int q0 = blockIdx.x * 64;
  const int z  = blockIdx.z;
  const int hoff = h * D_HEAD;
  const int kbase = z * (L_SEQ / KSPLIT);
  const int t = threadIdx.x;
  const int wave = t >> 6;
  const int lane = t & 63;
  const int quad = lane >> 4;
  const int col  = lane & 15;

  // Q fragments (B-operand of S^T: n = q = col, k = d = quad*8+j)
  bf16x8 qf[2];
  {
    const u16* qrow = Q + (size_t)(q0 + wave * 16 + col) * E_DIM + hoff;
    qf[0] = *(const bf16x8*)(qrow + quad * 8);
    qf[1] = *(const bf16x8*)(qrow + 32 + quad * 8);
  }

  float l_lane = 0.f;                 // partial row-sum for q = q0+wave*16+col
  f32x4 oacc[4];                      // O^T: d = td*16+quad*4+r, q = col
#pragma unroll
  for (int td = 0; td < 4; ++td) oacc[td] = (f32x4){0.f, 0.f, 0.f, 0.f};

  const u16* brow = Bb + (size_t)(q0 + wave * 16 + col) * L_SEQ;  // prescaled bias
  const int cst = t & 7, rst = t >> 3;

  for (int kt = 0; kt < L_SEQ / KSPLIT / FK; ++kt) {
    const int k0 = kbase + kt * FK;
    __syncthreads();
#pragma unroll
    for (int s = 0; s < 2; ++s) {
      int rr = rst + s * 32;
      *(u16x8*)&Ks[rr][cst * 8] = *(const u16x8*)&Kp[(size_t)(k0 + rr) * E_DIM + hoff + cst * 8];
      *(u16x8*)&Vs[rr][cst * 8] = *(const u16x8*)&Vt[(size_t)(hoff + rr) * L_SEQ + k0 + cst * 8];
    }
    // prescaled bias: lane needs l = tt*16+quad*4..+3 for its q -> 8B loads
    float pb[4][4];
#pragma unroll
    for (int tt = 0; tt < 4; ++tt) {
      u16x4 bv = *(const u16x4*)&brow[k0 + tt * 16 + quad * 4];
#pragma unroll
      for (int r = 0; r < 4; ++r) pb[tt][r] = bf2f(bv[r]);
    }
    __syncthreads();

#pragma unroll
    for (int tt = 0; tt < 4; ++tt) {
      // S^T tile: A = K-frag (m=l), B = Q-frag (n=q). D: l=quad*4+r, q=col.
      f32x4 a = (f32x4){0.f, 0.f, 0.f, 0.f};
      a = __builtin_amdgcn_mfma_f32_16x16x32_bf16(*(const bf16x8*)&Ks[tt * 16 + col][quad * 8], qf[0], a, 0, 0, 0);
      a = __builtin_amdgcn_mfma_f32_16x16x32_bf16(*(const bf16x8*)&Ks[tt * 16 + col][32 + quad * 8], qf[1], a, 0, 0, 0);
      float p[4];
#pragma unroll
      for (int r = 0; r < 4; ++r) {
        p[r] = __builtin_amdgcn_exp2f(fmaf(a[r], C_LOG2E_32, pb[tt][r]));
        l_lane += p[r];
      }
#if HAVE_MFMA16
      union { u32 u[2]; bf16x4 v; } pk;
      pk.u[0] = pack_bf16_pair(p[0], p[1]);
      pk.u[1] = pack_bf16_pair(p[2], p[3]);
      // O^T += V^T(tile) * P^T : A = V^T frag (m=d, k=l=tt*16+quad*4+j),
      // B = pk (n=q=col, k=quad*4+j) -- exactly the S^T acc layout.
#pragma unroll
      for (int td = 0; td < 4; ++td) {
        bf16x4 vf = *(const bf16x4*)&Vs[td * 16 + col][tt * 16 + quad * 4];
        oacc[td] = __builtin_amdgcn_mfma_f32_16x16x16bf16_1k(vf, pk.v, oacc[td], 0, 0, 0);
      }
#else
      uint2 w;
      w.x = pack_bf16_pair(p[0], p[1]);
      w.y = pack_bf16_pair(p[2], p[3]);
      *(uint2*)&Ps[wave][col][tt * 16 + quad * 4] = w;
#endif
    }

#if !HAVE_MFMA16
    // fallback: O += P V via 16x16x32 (P strip through LDS)
#pragma unroll
    for (int kk = 0; kk < 2; ++kk) {
      bf16x8 pf = *(const bf16x8*)&Ps[wave][col][kk * 32 + quad * 8];
#pragma unroll
      for (int td = 0; td < 4; ++td) {
        bf16x8 vf = *(const bf16x8*)&Vs[td * 16 + col][kk * 32 + quad * 8];
        oacc[td] = __builtin_amdgcn_mfma_f32_16x16x32_bf16(pf, vf, oacc[td], 0, 0, 0);
      }
    }
#endif
  }

  l_lane += __shfl_xor(l_lane, 16);
  l_lane += __shfl_xor(l_lane, 32);
  if (lane < 16)
    lp[((size_t)z * L_SEQ + q0 + wave * 16 + lane) * H_HEADS + h] = l_lane;

#if HAVE_MFMA16
  // O^T epilogue: lane has q = col, d = td*16+quad*4+r -> 8B contiguous stores
  const int qmine = q0 + wave * 16 + col;
#pragma unroll
  for (int td = 0; td < 4; ++td) {
    u16x4 pk;
#pragma unroll
    for (int r = 0; r < 4; ++r) pk[r] = f2bf(oacc[td][r]);
    *(u16x4*)&Op[((size_t)z * L_SEQ + qmine) * E_DIM + hoff + td * 16 + quad * 4] = pk;
  }
#else
  const int qrow_mine = q0 + wave * 16 + quad * 4;
#pragma unroll
  for (int td = 0; td < 4; ++td)
#pragma unroll
    for (int r = 0; r < 4; ++r)
      Op[((size_t)z * L_SEQ + qrow_mine + r) * E_DIM + hoff + td * 16 + col] = f2bf(oacc[td][r]);
#endif
}

// ---------------------------------------------------------------------------
// Merge split-K partials: AO = (sum_s O_s) / (sum_s l_s), bf16 out.
// ---------------------------------------------------------------------------
__global__ void merge_attn(const u16* __restrict__ Op, const float* __restrict__ lp,
                           u16* __restrict__ AOb)
{
  size_t gid = (size_t)blockIdx.x * 256 + threadIdx.x;
  size_t idx = gid * 4;
  int q = (int)(idx >> 10);
  int e = (int)(idx & 1023);
  int h = e >> 6;
  float o[4] = {0.f, 0.f, 0.f, 0.f};
  float lsum = 0.f;
#pragma unroll
  for (int s = 0; s < KSPLIT; ++s) {
    u16x4 pv = *(const u16x4*)&Op[((size_t)s * L_SEQ + q) * E_DIM + e];
#pragma unroll
    for (int j = 0; j < 4; ++j) o[j] += bf2f(pv[j]);
    lsum += lp[((size_t)s * L_SEQ + q) * H_HEADS + h];
  }
  float inv = 1.f / lsum;
  u16x4 pk;
#pragma unroll
  for (int j = 0; j < 4; ++j) pk[j] = f2bf(o[j] * inv);
  *(u16x4*)&AOb[idx] = pk;
}

// ---------------------------------------------------------------------------
extern "C" void kernel_launch(void* const* d_in, const int* in_sizes, int n_in,
                              void* d_out, int out_size, void* d_ws, size_t ws_size,
                              hipStream_t stream)
{
  const float* values = (const float*)d_in[0];
  const float* keys   = (const float*)d_in[1];
  const float* query  = (const float*)d_in[2];
  const float* dist   = (const float*)d_in[3];
  const float* Wv     = (const float*)d_in[4];
  const float* Wk     = (const float*)d_in[5];
  const float* Wq     = (const float*)d_in[6];
  const float* Wo     = (const float*)d_in[7];
  const float* bo     = (const float*)d_in[8];
  float* out = (float*)d_out;

  const size_t MB = (size_t)1 << 20;
  char* w = (char*)d_ws;
  u16* xq  = (u16*)(w + 0 * MB);    // 4 MB  (dead after proj)
  u16* xk  = (u16*)(w + 4 * MB);    // 4 MB  (dead after proj)
  u16* xv  = (u16*)(w + 8 * MB);    // 4 MB  (dead after proj)
  u16* wqb = (u16*)(w + 12 * MB);   // 2 MB  (dead after proj)
  u16* wkb = (u16*)(w + 14 * MB);   // 2 MB  (dead after proj)
  u16* wvb = (u16*)(w + 16 * MB);   // 2 MB  (dead after proj)
  u16* wob = (u16*)(w + 18 * MB);   // 2 MB  (live to end)
  u16* Bb  = (u16*)(w + 20 * MB);   // 8 MB  prescaled bias bf16 [L][L]
  u16* Qh  = (u16*)(w + 28 * MB);   // 4 MB
  u16* Kh  = (u16*)(w + 32 * MB);   // 4 MB
  u16* Vth = (u16*)(w + 36 * MB);   // 4 MB  V^T [E][L]
  u16* AOb = (u16*)(w + 40 * MB);   // 4 MB
  float* lp = (float*)(w + 44 * MB);// 0.5 MB
  u16* Op  = (u16*)(w + 0 * MB);    // 16 MB, overlaps dead xq..wvb region

  // 1) convert + bias precompute + out prefill  (16384 blocks)
  cvt_all<<<16384, 256, 0, stream>>>(query, keys, values, Wq, Wk, Wv, Wo, dist, bo,
                                     xq, xk, xv, wqb, wkb, wvb, wob, Bb, out);

  // 2) Q/K/V projections (z=2 -> V^T)
  dim3 gProj(E_DIM / TN, L_SEQ / TM, 3);
  gemm_pd<0><<<gProj, 256, 0, stream>>>(xq, wqb, Qh,
                                        xk, wkb, Kh,
                                        xv, wvb, Vth,
                                        L_SEQ, E_DIM, E_DIM);

  // 3) split-K flash attention
  dim3 gAttn(L_SEQ / 64, H_HEADS, KSPLIT);
  flash4<<<gAttn, 256, 0, stream>>>(Qh, Kh, Vth, Bb, Op, lp);

  // 4) merge partials -> bf16 AO
  merge_attn<<<(L_SEQ * E_DIM / 4) / 256, 256, 0, stream>>>(Op, lp, AOb);

  // 5) out += AO @ Wo^T, split-K=2 (256 blocks), atomic f32 accumulate
  dim3 gOut(E_DIM / TN, L_SEQ / TM, OSPLIT);
  gemm_pd<2><<<gOut, 256, 0, stream>>>(AOb, wob, out,
                                       AOb, wob, out,
                                       AOb, wob, out,
                                       L_SEQ, E_DIM, E_DIM);
}

// Round 7
// 217.354 us; speedup vs baseline: 1.0261x; 1.0207x over previous
//
#include <hip/hip_runtime.h>

// ---------------------------------------------------------------------------
// SelfAttention, L=2048, E=1024, H=16, D=64. fp32 in/out, bf16 MFMA compute.
//   cvt_all   : f32->bf16 (q,k,v,W*) + bias=(1/(1+dist))*log2e/32 bf16 + out=bo
//   gemm_pd<0>: Q,K,V projections (z selects tensor; z=2 writes V^T)
//   flash5    : split-K flash, S^T softmax; FK=32 tiles, double-buffered
//               global_load_lds staging, ONE barrier/iter, bias reg-prefetch
//   merge_attn: sum partials, divide, write bf16 AO
//   gemm_pd<2>: out += AO @ Wo^T, split-K=2 over z, unsafeAtomicAdd f32
// GEMM core: 64x128 tile, BK=32 double-buffered LDS, one barrier/iter,
// prefetch after barrier; XOR-swizzled granules (conflict-free b128 reads).
// ---------------------------------------------------------------------------

#define L_SEQ 2048
#define E_DIM 1024
#define H_HEADS 16
#define D_HEAD 64
#define KSPLIT 4     // flash k-split
#define OSPLIT 2     // out-proj k-split

typedef unsigned short u16;
typedef unsigned int u32;
typedef __attribute__((ext_vector_type(8))) short bf16x8;
typedef __attribute__((ext_vector_type(8))) unsigned short u16x8;
typedef __attribute__((ext_vector_type(4))) unsigned short u16x4;
typedef __attribute__((ext_vector_type(4))) float f32x4;

#define C_LOG2E_32 0.045084220027780106f   // log2(e)/32

__device__ __forceinline__ float bf2f(u16 u) {
  union { u32 i; float f; } v; v.i = ((u32)u) << 16; return v.f;
}
__device__ __forceinline__ u16 f2bf(float f) {
  union { float f; u32 i; } v; v.f = f;
  u32 u = v.i;
  u += 0x7FFFu + ((u >> 16) & 1u);   // RNE
  return (u16)(u >> 16);
}
// pack bf16(lo), bf16(hi) into one u32 (round-half-up; operands > 0)
__device__ __forceinline__ u32 pack_bf16_pair(float lo, float hi) {
  union { float f; u32 u; } a, b;
  a.f = lo; b.f = hi;
  return __builtin_amdgcn_perm(b.u + 0x8000u, a.u + 0x8000u, 0x07060302u);
}
// async global->LDS 16B/lane; LDS dest = (wave-uniform base) + lane*16
__device__ __forceinline__ void gload16(const u16* g, u16* l) {
  __builtin_amdgcn_global_load_lds(
      (const __attribute__((address_space(1))) u32*)g,
      (__attribute__((address_space(3))) u32*)l, 16, 0, 0);
}

// ---------------------------------------------------------------------------
// One-shot conversion + out-buffer bias prefill.
// ---------------------------------------------------------------------------
__global__ void cvt_all(const float* __restrict__ xq, const float* __restrict__ xk,
                        const float* __restrict__ xv,
                        const float* __restrict__ wq, const float* __restrict__ wk,
                        const float* __restrict__ wv, const float* __restrict__ wo,
                        const float* __restrict__ dist, const float* __restrict__ bo,
                        u16* oq, u16* ok, u16* ov,
                        u16* owq, u16* owk, u16* owv, u16* owo, u16* obias,
                        float* __restrict__ outp)
{
  size_t gid = (size_t)blockIdx.x * 256 + threadIdx.x;   // one x4 group
  const size_t NQ = 524288;    // (L*E)/4
  const size_t NW = 262144;    // (E*E)/4
  const size_t DL = 1048576;   // (L*L)/4
  const size_t FILL = 3 * NQ + 4 * NW + DL;

  if (gid >= FILL) {           // out[q][:] = bo (out-proj accumulates on top)
    size_t off = (gid - FILL) * 4;
    int n = (int)(off & (E_DIM - 1));
    *(f32x4*)&outp[off] = *(const f32x4*)&bo[n];
    return;
  }

  const float* src; u16* dst; size_t off; bool isb = false;
  if      (gid <     NQ)           { src = xq;   dst = oq;    off = gid; }
  else if (gid < 2 * NQ)           { src = xk;   dst = ok;    off = gid - NQ; }
  else if (gid < 3 * NQ)           { src = xv;   dst = ov;    off = gid - 2 * NQ; }
  else if (gid < 3 * NQ + NW)      { src = wq;   dst = owq;   off = gid - 3 * NQ; }
  else if (gid < 3 * NQ + 2 * NW)  { src = wk;   dst = owk;   off = gid - 3 * NQ - NW; }
  else if (gid < 3 * NQ + 3 * NW)  { src = wv;   dst = owv;   off = gid - 3 * NQ - 2 * NW; }
  else if (gid < 3 * NQ + 4 * NW)  { src = wo;   dst = owo;   off = gid - 3 * NQ - 3 * NW; }
  else { src = dist; dst = obias; off = gid - 3 * NQ - 4 * NW; isb = true; }

  f32x4 v = *(const f32x4*)&src[off * 4];
  u16x4 o;
#pragma unroll
  for (int j = 0; j < 4; ++j) {
    float f = v[j];
    if (isb) f = (f == 0.f) ? 0.f : C_LOG2E_32 / (f + 1.f);
    o[j] = f2bf(f);
  }
  *(u16x4*)&dst[off * 4] = o;
}

// ---------------------------------------------------------------------------
// NT GEMM, bf16, pipelined: C[M,N] = A[M,K]*B[N,K]^T. 64x128 tile, BK=32,
// double-buffered LDS (24 KB), one barrier/iter, prefetch after barrier.
// LDS slot s of row r holds global granule s^((r>>1)&3): frag reads 2-way.
// OUTMODE 0: triple (z selects A/B/C), bf16 out, z==2 writes C^T.
// OUTMODE 2: single tensor, z = K-split (K/OSPLIT each), f32 atomic-add out.
// ---------------------------------------------------------------------------
#define TM 64
#define TN 128
#define BK 32

template<int OUTMODE>
__global__ __launch_bounds__(256, 4) void gemm_pd(
    const u16* __restrict__ A0, const u16* __restrict__ B0, void* __restrict__ C0,
    const u16* __restrict__ A1, const u16* __restrict__ B1, void* __restrict__ C1,
    const u16* __restrict__ A2, const u16* __restrict__ B2, void* __restrict__ C2,
    int M, int N, int K)
{
  const u16* A; const u16* B; void* C;
  if (OUTMODE == 2)         { A = A0; B = B0; C = C0; }
  else if (blockIdx.z == 0) { A = A0; B = B0; C = C0; }
  else if (blockIdx.z == 1) { A = A1; B = B1; C = C1; }
  else                      { A = A2; B = B2; C = C2; }

  __shared__ __align__(16) u16 As[2][TM * BK];   // 4 KB per buf
  __shared__ __align__(16) u16 Bs[2][TN * BK];   // 8 KB per buf

  const int m0 = blockIdx.y * TM;
  const int n0 = blockIdx.x * TN;
  const int t = threadIdx.x;
  const int wave = t >> 6;
  const int lane = t & 63;
  const int quad = lane >> 4;
  const int col  = lane & 15;
  const int wm = (wave >> 1) * 32;
  const int wn = (wave & 1) * 64;

  // staging: one gload16 covers 16 rows x 32 cols per wave chunk;
  // lane -> row lane/4, slot lane&3, global granule (lane&3)^((lane>>3)&3)
  const int sr = lane >> 2;
  const int sg = ((lane & 3) ^ ((lane >> 3) & 3)) * 8;
  const u16* gA  = A + (size_t)(m0 + wave * 16 + sr) * K + sg;
  const u16* gB0 = B + (size_t)(n0 + wave * 16 + sr) * K + sg;
  const u16* gB1 = B + (size_t)(n0 + 64 + wave * 16 + sr) * K + sg;
  const int lA  = (wave * 16) * BK;
  const int lB0 = (wave * 16) * BK;
  const int lB1 = (64 + wave * 16) * BK;

  const int kbeg = (OUTMODE == 2) ? blockIdx.z * (K / OSPLIT) : 0;
  const int kend = (OUTMODE == 2) ? kbeg + K / OSPLIT : K;

  f32x4 acc[2][4];
#pragma unroll
  for (int i = 0; i < 2; ++i)
#pragma unroll
    for (int j = 0; j < 4; ++j) acc[i][j] = (f32x4){0.f, 0.f, 0.f, 0.f};

  // prologue: stage first tile into buf 0
  gload16(gA + kbeg, &As[0][lA]);
  gload16(gB0 + kbeg, &Bs[0][lB0]);
  gload16(gB1 + kbeg, &Bs[0][lB1]);

  const int slot8 = (quad ^ ((col >> 1) & 3)) * 8;   // frag granule (swizzled)

  int buf = 0;
  for (int k0 = kbeg; k0 < kend; k0 += BK) {
    __syncthreads();   // drains vmcnt: tile(buf) visible; prev reads done
    int nk = k0 + BK;
    if (nk < kend) {   // prefetch next tile; in flight across whole compute
      gload16(gA + nk, &As[buf ^ 1][lA]);
      gload16(gB0 + nk, &Bs[buf ^ 1][lB0]);
      gload16(gB1 + nk, &Bs[buf ^ 1][lB1]);
    }

    bf16x8 af[2], bfr[4];
#pragma unroll
    for (int i = 0; i < 2; ++i)
      af[i] = *(const bf16x8*)&As[buf][(wm + i * 16 + col) * BK + slot8];
#pragma unroll
    for (int j = 0; j < 4; ++j)
      bfr[j] = *(const bf16x8*)&Bs[buf][(wn + j * 16 + col) * BK + slot8];

#pragma unroll
    for (int i = 0; i < 2; ++i)
#pragma unroll
      for (int j = 0; j < 4; ++j)
        acc[i][j] = __builtin_amdgcn_mfma_f32_16x16x32_bf16(af[i], bfr[j], acc[i][j], 0, 0, 0);

    buf ^= 1;
  }

  const bool transC = (OUTMODE == 0) && (blockIdx.z == 2);
#pragma unroll
  for (int i = 0; i < 2; ++i) {
    int rowb = m0 + wm + i * 16 + quad * 4;
#pragma unroll
    for (int j = 0; j < 4; ++j) {
      int cn = n0 + wn + j * 16 + col;
      if (OUTMODE == 2) {
#pragma unroll
        for (int r = 0; r < 4; ++r)
          unsafeAtomicAdd(&((float*)C)[(size_t)(rowb + r) * N + cn], acc[i][j][r]);
      } else if (transC) {
        u16x4 pk;
#pragma unroll
        for (int r = 0; r < 4; ++r) pk[r] = f2bf(acc[i][j][r]);
        *(u16x4*)&((u16*)C)[(size_t)cn * M + rowb] = pk;   // C^T: 4 contiguous
      } else {
#pragma unroll
        for (int r = 0; r < 4; ++r)
          ((u16*)C)[(size_t)(rowb + r) * N + cn] = f2bf(acc[i][j][r]);
      }
    }
  }
}

// ---------------------------------------------------------------------------
// Split-K flash attention, S^T form, PIPELINED:
// FK=32 k-tiles, K/V staged via global_load_lds (1 instr each) into
// double-buffered swizzled LDS; ONE barrier per iter, prefetch after barrier;
// bias prefetched into registers one tile ahead. No-max softmax.
// LDS 21.5 KB -> 7 blocks/CU.
// ---------------------------------------------------------------------------
#define FK 32
#define PLDV 40   // Ps pad: 80B rows (16B-aligned)

__global__ __launch_bounds__(256, 7) void flash5(
    const u16* __restrict__ Q, const u16* __restrict__ Kp,
    const u16* __restrict__ Vt, const u16* __restrict__ Bb,
    u16* __restrict__ Op, float* __restrict__ lp)
{
  __shared__ __align__(16) u16 Ks[2][FK * 64];      // K-tile [l][d], swizzled
  __shared__ __align__(16) u16 Vs[2][D_HEAD * FK];  // V^T tile [d][l], swizzled
  __shared__ __align__(16) u16 Ps[4][16][PLDV];     // per-wave P strip [q][l]

  const int h  = blockIdx.y;
  const int q0 = blockIdx.x * 64;
  const int z  = blockIdx.z;
  const int hoff = h * D_HEAD;
  const int kbase = z * (L_SEQ / KSPLIT);
  const int NT = (L_SEQ / KSPLIT) / FK;   // 16 tiles
  const int t = threadIdx.x;
  const int wave = t >> 6;
  const int lane = t & 63;
  const int quad = lane >> 4;
  const int col  = lane & 15;

  // Q fragments (B-operand of S^T: n = q = col, k = d = quad*8+j)
  bf16x8 qf[2];
  {
    const u16* qrow = Q + (size_t)(q0 + wave * 16 + col) * E_DIM + hoff;
    qf[0] = *(const bf16x8*)(qrow + quad * 8);
    qf[1] = *(const bf16x8*)(qrow + 32 + quad * 8);
  }

  // K staging map: 32 rows x 8 granules; wave covers 8 rows.
  // lane -> row wave*8 + lane/8, slot lane&7, global granule (lane&7)^(lane>>3)
  const int krow = wave * 8 + (lane >> 3);
  const int kg = ((lane & 7) ^ (lane >> 3)) * 8;
  const u16* gK = Kp + (size_t)krow * E_DIM + hoff + kg;   // + (k0)*E_DIM
  u16* lK = &Ks[0][wave * 8 * 64];   // buf stride = FK*64 elems

  // V staging map: 64 rows x 4 granules; wave covers 16 rows.
  // lane -> row wave*16 + lane/4, slot lane&3, granule (lane&3)^((lane>>4)&3)
  const int vrow = wave * 16 + (lane >> 2);
  const int vg = ((lane & 3) ^ ((lane >> 4) & 3)) * 8;
  const u16* gV = Vt + (size_t)(hoff + vrow) * L_SEQ + vg;  // + k0
  u16* lV = &Vs[0][wave * 16 * FK];

  float l_lane = 0.f;                 // partial row-sum for q = q0+wave*16+col
  f32x4 oacc[4];
#pragma unroll
  for (int td = 0; td < 4; ++td) oacc[td] = (f32x4){0.f, 0.f, 0.f, 0.f};

  const u16* brow = Bb + (size_t)(q0 + wave * 16 + col) * L_SEQ;  // prescaled

  // prologue: stage tile 0 + bias regs for tile 0
  gload16(gK + (size_t)kbase * E_DIM, lK);
  gload16(gV + kbase, lV);
  u16x4 bv[2], bn[2] = {(u16x4){0,0,0,0}, (u16x4){0,0,0,0}};
  bv[0] = *(const u16x4*)&brow[kbase + quad * 4];
  bv[1] = *(const u16x4*)&brow[kbase + 16 + quad * 4];

  const int ks0 = (quad ^ (col & 7)) * 8;          // K frag slots (swizzled)
  const int ks1 = ((quad + 4) ^ (col & 7)) * 8;
  const int vsl = (quad ^ ((col >> 2) & 3)) * 8;   // V frag slot

  int buf = 0;
  for (int kt = 0; kt < NT; ++kt) {
    const int k0 = kbase + kt * FK;
    __syncthreads();   // tile(buf) visible; prev iter's LDS reads done
    if (kt + 1 < NT) { // prefetch next tile into buf^1 + next bias into regs
      const int nk = k0 + FK;
      gload16(gK + (size_t)nk * E_DIM, lK + (buf ^ 1 ? 0 : 0) + (buf ^ 1) * (FK * 64) - buf * 0);
      // (clearer form below; the compiler folds these)
      gload16(gV + nk, lV + (buf ^ 1) * (D_HEAD * FK));
      bn[0] = *(const u16x4*)&brow[nk + quad * 4];
      bn[1] = *(const u16x4*)&brow[nk + 16 + quad * 4];
    }
    const u16* Kb = &Ks[buf][0];
    const u16* Vb = &Vs[buf][0];

    // S^T tiles (tt over 32 l-cols): A = K-frag (m=l), B = Q-frag (n=q)
#pragma unroll
    for (int tt = 0; tt < 2; ++tt) {
      const u16* kr = &Kb[(tt * 16 + col) * 64];
      f32x4 a = (f32x4){0.f, 0.f, 0.f, 0.f};
      a = __builtin_amdgcn_mfma_f32_16x16x32_bf16(*(const bf16x8*)&kr[ks0], qf[0], a, 0, 0, 0);
      a = __builtin_amdgcn_mfma_f32_16x16x32_bf16(*(const bf16x8*)&kr[ks1], qf[1], a, 0, 0, 0);
      float p[4];
#pragma unroll
      for (int r = 0; r < 4; ++r) {
        p[r] = __builtin_amdgcn_exp2f(fmaf(a[r], C_LOG2E_32, bf2f(bv[tt][r])));
        l_lane += p[r];
      }
      uint2 w;
      w.x = pack_bf16_pair(p[0], p[1]);
      w.y = pack_bf16_pair(p[2], p[3]);
      *(uint2*)&Ps[wave][col][tt * 16 + quad * 4] = w;   // P[q=col][l..l+3]
    }
    // same-wave LDS RAW (P write -> read): lgkmcnt-ordered, no barrier.

    // O += P V : A = P strip [q][l], B = V^T [d][l]
    {
      bf16x8 pf = *(const bf16x8*)&Ps[wave][col][quad * 8];
#pragma unroll
      for (int td = 0; td < 4; ++td) {
        bf16x8 vf = *(const bf16x8*)&Vb[(td * 16 + col) * FK + vsl];
        oacc[td] = __builtin_amdgcn_mfma_f32_16x16x32_bf16(pf, vf, oacc[td], 0, 0, 0);
      }
    }

    bv[0] = bn[0]; bv[1] = bn[1];
    buf ^= 1;
  }

  l_lane += __shfl_xor(l_lane, 16);
  l_lane += __shfl_xor(l_lane, 32);
  if (lane < 16)
    lp[((size_t)z * L_SEQ + q0 + wave * 16 + lane) * H_HEADS + h] = l_lane;

  const int qrow_mine = q0 + wave * 16 + quad * 4;
#pragma unroll
  for (int td = 0; td < 4; ++td)
#pragma unroll
    for (int r = 0; r < 4; ++r)
      Op[((size_t)z * L_SEQ + qrow_mine + r) * E_DIM + hoff + td * 16 + col] = f2bf(oacc[td][r]);
}

// ---------------------------------------------------------------------------
// Merge split-K partials: AO = (sum_s O_s) / (sum_s l_s), bf16 out.
// ---------------------------------------------------------------------------
__global__ void merge_attn(const u16* __restrict__ Op, const float* __restrict__ lp,
                           u16* __restrict__ AOb)
{
  size_t gid = (size_t)blockIdx.x * 256 + threadIdx.x;
  size_t idx = gid * 4;
  int q = (int)(idx >> 10);
  int e = (int)(idx & 1023);
  int h = e >> 6;
  float o[4] = {0.f, 0.f, 0.f, 0.f};
  float lsum = 0.f;
#pragma unroll
  for (int s = 0; s < KSPLIT; ++s) {
    u16x4 pv = *(const u16x4*)&Op[((size_t)s * L_SEQ + q) * E_DIM + e];
#pragma unroll
    for (int j = 0; j < 4; ++j) o[j] += bf2f(pv[j]);
    lsum += lp[((size_t)s * L_SEQ + q) * H_HEADS + h];
  }
  float inv = 1.f / lsum;
  u16x4 pk;
#pragma unroll
  for (int j = 0; j < 4; ++j) pk[j] = f2bf(o[j] * inv);
  *(u16x4*)&AOb[idx] = pk;
}

// ---------------------------------------------------------------------------
extern "C" void kernel_launch(void* const* d_in, const int* in_sizes, int n_in,
                              void* d_out, int out_size, void* d_ws, size_t ws_size,
                              hipStream_t stream)
{
  const float* values = (const float*)d_in[0];
  const float* keys   = (const float*)d_in[1];
  const float* query  = (const float*)d_in[2];
  const float* dist   = (const float*)d_in[3];
  const float* Wv     = (const float*)d_in[4];
  const float* Wk     = (const float*)d_in[5];
  const float* Wq     = (const float*)d_in[6];
  const float* Wo     = (const float*)d_in[7];
  const float* bo     = (const float*)d_in[8];
  float* out = (float*)d_out;

  const size_t MB = (size_t)1 << 20;
  char* w = (char*)d_ws;
  u16* xq  = (u16*)(w + 0 * MB);    // 4 MB  (dead after proj)
  u16* xk  = (u16*)(w + 4 * MB);    // 4 MB  (dead after proj)
  u16* xv  = (u16*)(w + 8 * MB);    // 4 MB  (dead after proj)
  u16* wqb = (u16*)(w + 12 * MB);   // 2 MB  (dead after proj)
  u16* wkb = (u16*)(w + 14 * MB);   // 2 MB  (dead after proj)
  u16* wvb = (u16*)(w + 16 * MB);   // 2 MB  (dead after proj)
  u16* wob = (u16*)(w + 18 * MB);   // 2 MB  (live to end)
  u16* Bb  = (u16*)(w + 20 * MB);   // 8 MB  prescaled bias bf16 [L][L]
  u16* Qh  = (u16*)(w + 28 * MB);   // 4 MB
  u16* Kh  = (u16*)(w + 32 * MB);   // 4 MB
  u16* Vth = (u16*)(w + 36 * MB);   // 4 MB  V^T [E][L]
  u16* AOb = (u16*)(w + 40 * MB);   // 4 MB
  float* lp = (float*)(w + 44 * MB);// 0.5 MB
  u16* Op  = (u16*)(w + 0 * MB);    // 16 MB, overlaps dead xq..wvb region

  // 1) convert + bias precompute + out prefill
  cvt_all<<<16384, 256, 0, stream>>>(query, keys, values, Wq, Wk, Wv, Wo, dist, bo,
                                     xq, xk, xv, wqb, wkb, wvb, wob, Bb, out);

  // 2) Q/K/V projections (z=2 -> V^T), 64x128 tiles -> 768 blocks
  dim3 gProj(E_DIM / TN, L_SEQ / TM, 3);
  gemm_pd<0><<<gProj, 256, 0, stream>>>(xq, wqb, Qh,
                                        xk, wkb, Kh,
                                        xv, wvb, Vth,
                                        L_SEQ, E_DIM, E_DIM);

  // 3) split-K pipelined flash attention (2048 blocks)
  dim3 gAttn(L_SEQ / 64, H_HEADS, KSPLIT);
  flash5<<<gAttn, 256, 0, stream>>>(Qh, Kh, Vth, Bb, Op, lp);

  // 4) merge partials -> bf16 AO
  merge_attn<<<(L_SEQ * E_DIM / 4) / 256, 256, 0, stream>>>(Op, lp, AOb);

  // 5) out += AO @ Wo^T, split-K=2 (512 blocks), atomic f32 accumulate
  dim3 gOut(E_DIM / TN, L_SEQ / TM, OSPLIT);
  gemm_pd<2><<<gOut, 256, 0, stream>>>(AOb, wob, out,
                                       AOb, wob, out,
                                       AOb, wob, out,
                                       L_SEQ, E_DIM, E_DIM);
}

// Round 8
// 207.233 us; speedup vs baseline: 1.0762x; 1.0488x over previous
//
#include <hip/hip_runtime.h>

// ---------------------------------------------------------------------------
// SelfAttention, L=2048, E=1024, H=16, D=64. fp32 in/out, bf16 MFMA compute.
//   cvt_all   : f32->bf16 (q,k,v,W*) + bias=(1/(1+dist))*log2e/32 bf16 + out=bo
//   gemm_pd<0>: Q,K,V projections (z selects tensor; z=2 writes V^T)
//   flash6    : split-K flash, S^T softmax; 32 q-rows/wave (128/block) for 2x
//               staging reuse; FK=32 double-buffered global_load_lds tiles
//   merge_attn: sum partials, divide, write bf16 AO
//   gemm_pd<2>: out += AO @ Wo^T, split-K=2 over z, unsafeAtomicAdd f32
// GEMM core: 128x128 tile, BK=32 double-buffered LDS, one barrier/iter,
// prefetch after barrier; XOR-swizzled granules (conflict-free b128 reads).
// ---------------------------------------------------------------------------

#define L_SEQ 2048
#define E_DIM 1024
#define H_HEADS 16
#define D_HEAD 64
#define KSPLIT 4     // flash k-split
#define OSPLIT 2     // out-proj k-split

typedef unsigned short u16;
typedef unsigned int u32;
typedef __attribute__((ext_vector_type(8))) short bf16x8;
typedef __attribute__((ext_vector_type(8))) unsigned short u16x8;
typedef __attribute__((ext_vector_type(4))) unsigned short u16x4;
typedef __attribute__((ext_vector_type(4))) float f32x4;

#define C_LOG2E_32 0.045084220027780106f   // log2(e)/32

__device__ __forceinline__ float bf2f(u16 u) {
  union { u32 i; float f; } v; v.i = ((u32)u) << 16; return v.f;
}
__device__ __forceinline__ u16 f2bf(float f) {
  union { float f; u32 i; } v; v.f = f;
  u32 u = v.i;
  u += 0x7FFFu + ((u >> 16) & 1u);   // RNE
  return (u16)(u >> 16);
}
// pack bf16(lo), bf16(hi) into one u32 (round-half-up; operands > 0)
__device__ __forceinline__ u32 pack_bf16_pair(float lo, float hi) {
  union { float f; u32 u; } a, b;
  a.f = lo; b.f = hi;
  return __builtin_amdgcn_perm(b.u + 0x8000u, a.u + 0x8000u, 0x07060302u);
}
// async global->LDS 16B/lane; LDS dest = (wave-uniform base) + lane*16
__device__ __forceinline__ void gload16(const u16* g, u16* l) {
  __builtin_amdgcn_global_load_lds(
      (const __attribute__((address_space(1))) u32*)g,
      (__attribute__((address_space(3))) u32*)l, 16, 0, 0);
}

// ---------------------------------------------------------------------------
// One-shot conversion + out prefill. 32B/thread (2 f32x4 in, 1 u16x8 out).
// ---------------------------------------------------------------------------
__global__ void cvt_all(const float* __restrict__ xq, const float* __restrict__ xk,
                        const float* __restrict__ xv,
                        const float* __restrict__ wq, const float* __restrict__ wk,
                        const float* __restrict__ wv, const float* __restrict__ wo,
                        const float* __restrict__ dist, const float* __restrict__ bo,
                        u16* oq, u16* ok, u16* ov,
                        u16* owq, u16* owk, u16* owv, u16* owo, u16* obias,
                        float* __restrict__ outp)
{
  size_t gid = (size_t)blockIdx.x * 256 + threadIdx.x;   // one x8 group
  const size_t NQ = 262144;    // (L*E)/8
  const size_t NW = 131072;    // (E*E)/8
  const size_t DL = 524288;    // (L*L)/8
  const size_t FILL = 3 * NQ + 4 * NW + DL;   // 1835008

  if (gid >= FILL) {           // out[q][:] = bo (out-proj accumulates on top)
    size_t off = (gid - FILL) * 8;
    int n = (int)(off & (E_DIM - 1));
    *(f32x4*)&outp[off] = *(const f32x4*)&bo[n];
    *(f32x4*)&outp[off + 4] = *(const f32x4*)&bo[n + 4];
    return;
  }

  const float* src; u16* dst; size_t off; bool isb = false;
  if      (gid <     NQ)           { src = xq;   dst = oq;    off = gid; }
  else if (gid < 2 * NQ)           { src = xk;   dst = ok;    off = gid - NQ; }
  else if (gid < 3 * NQ)           { src = xv;   dst = ov;    off = gid - 2 * NQ; }
  else if (gid < 3 * NQ + NW)      { src = wq;   dst = owq;   off = gid - 3 * NQ; }
  else if (gid < 3 * NQ + 2 * NW)  { src = wk;   dst = owk;   off = gid - 3 * NQ - NW; }
  else if (gid < 3 * NQ + 3 * NW)  { src = wv;   dst = owv;   off = gid - 3 * NQ - 2 * NW; }
  else if (gid < 3 * NQ + 4 * NW)  { src = wo;   dst = owo;   off = gid - 3 * NQ - 3 * NW; }
  else { src = dist; dst = obias; off = gid - 3 * NQ - 4 * NW; isb = true; }

  f32x4 v0 = *(const f32x4*)&src[off * 8];
  f32x4 v1 = *(const f32x4*)&src[off * 8 + 4];
  u16x8 o;
#pragma unroll
  for (int j = 0; j < 4; ++j) {
    float f0 = v0[j], f1 = v1[j];
    if (isb) {
      f0 = (f0 == 0.f) ? 0.f : C_LOG2E_32 / (f0 + 1.f);
      f1 = (f1 == 0.f) ? 0.f : C_LOG2E_32 / (f1 + 1.f);
    }
    o[j] = f2bf(f0); o[j + 4] = f2bf(f1);
  }
  *(u16x8*)&dst[off * 8] = o;
}

// ---------------------------------------------------------------------------
// NT GEMM, bf16, pipelined (round-6 config): C[M,N] = A[M,K]*B[N,K]^T.
// 128x128 tile, BK=32, double-buffered LDS (32 KB), one barrier/iter,
// prefetch after barrier. LDS slot s of row r holds granule s^((r>>1)&3).
// OUTMODE 0: triple (z selects A/B/C), bf16 out, z==2 writes C^T.
// OUTMODE 2: single tensor, z = K-split (K/OSPLIT each), f32 atomic-add out.
// ---------------------------------------------------------------------------
#define TM 128
#define TN 128
#define BK 32

template<int OUTMODE>
__global__ __launch_bounds__(256, 3) void gemm_pd(
    const u16* __restrict__ A0, const u16* __restrict__ B0, void* __restrict__ C0,
    const u16* __restrict__ A1, const u16* __restrict__ B1, void* __restrict__ C1,
    const u16* __restrict__ A2, const u16* __restrict__ B2, void* __restrict__ C2,
    int M, int N, int K)
{
  const u16* A; const u16* B; void* C;
  if (OUTMODE == 2)         { A = A0; B = B0; C = C0; }
  else if (blockIdx.z == 0) { A = A0; B = B0; C = C0; }
  else if (blockIdx.z == 1) { A = A1; B = B1; C = C1; }
  else                      { A = A2; B = B2; C = C2; }

  __shared__ __align__(16) u16 As[2][TM * BK];   // 8 KB per buf
  __shared__ __align__(16) u16 Bs[2][TN * BK];

  const int m0 = blockIdx.y * TM;
  const int n0 = blockIdx.x * TN;
  const int t = threadIdx.x;
  const int wave = t >> 6;
  const int lane = t & 63;
  const int quad = lane >> 4;
  const int col  = lane & 15;
  const int wm = (wave >> 1) * 64;
  const int wn = (wave & 1) * 64;

  // staging: one gload16 covers 16 rows x 32 cols; lane -> row lane/4,
  // slot lane&3, global granule (lane&3)^((lane>>3)&3)
  const int sr = lane >> 2;
  const int sg = ((lane & 3) ^ ((lane >> 3) & 3)) * 8;
  const u16* gA = A + (size_t)(m0 + wave * 32 + sr) * K + sg;
  const u16* gB = B + (size_t)(n0 + wave * 32 + sr) * K + sg;
  const int lo0 = (wave * 32) * BK;
  const int lo1 = (wave * 32 + 16) * BK;

  const int kbeg = (OUTMODE == 2) ? blockIdx.z * (K / OSPLIT) : 0;
  const int kend = (OUTMODE == 2) ? kbeg + K / OSPLIT : K;

  f32x4 acc[4][4];
#pragma unroll
  for (int i = 0; i < 4; ++i)
#pragma unroll
    for (int j = 0; j < 4; ++j) acc[i][j] = (f32x4){0.f, 0.f, 0.f, 0.f};

  // prologue: stage first tile into buf 0
  gload16(gA + kbeg, &As[0][lo0]);
  gload16(gA + (size_t)16 * K + kbeg, &As[0][lo1]);
  gload16(gB + kbeg, &Bs[0][lo0]);
  gload16(gB + (size_t)16 * K + kbeg, &Bs[0][lo1]);

  const int slot8 = (quad ^ ((col >> 1) & 3)) * 8;   // frag granule (swizzled)

  int buf = 0;
  for (int k0 = kbeg; k0 < kend; k0 += BK) {
    __syncthreads();   // tile(buf) visible; prev iter's LDS reads done
    int nk = k0 + BK;
    if (nk < kend) {   // prefetch next tile; in flight across whole compute
      gload16(gA + nk, &As[buf ^ 1][lo0]);
      gload16(gA + (size_t)16 * K + nk, &As[buf ^ 1][lo1]);
      gload16(gB + nk, &Bs[buf ^ 1][lo0]);
      gload16(gB + (size_t)16 * K + nk, &Bs[buf ^ 1][lo1]);
    }

    bf16x8 af[4], bfr[4];
#pragma unroll
    for (int i = 0; i < 4; ++i)
      af[i] = *(const bf16x8*)&As[buf][(wm + i * 16 + col) * BK + slot8];
#pragma unroll
    for (int j = 0; j < 4; ++j)
      bfr[j] = *(const bf16x8*)&Bs[buf][(wn + j * 16 + col) * BK + slot8];

#pragma unroll
    for (int i = 0; i < 4; ++i)
#pragma unroll
      for (int j = 0; j < 4; ++j)
        acc[i][j] = __builtin_amdgcn_mfma_f32_16x16x32_bf16(af[i], bfr[j], acc[i][j], 0, 0, 0);

    buf ^= 1;
  }

  const bool transC = (OUTMODE == 0) && (blockIdx.z == 2);
#pragma unroll
  for (int i = 0; i < 4; ++i) {
    int rowb = m0 + wm + i * 16 + quad * 4;
#pragma unroll
    for (int j = 0; j < 4; ++j) {
      int cn = n0 + wn + j * 16 + col;
      if (OUTMODE == 2) {
#pragma unroll
        for (int r = 0; r < 4; ++r)
          unsafeAtomicAdd(&((float*)C)[(size_t)(rowb + r) * N + cn], acc[i][j][r]);
      } else if (transC) {
        u16x4 pk;
#pragma unroll
        for (int r = 0; r < 4; ++r) pk[r] = f2bf(acc[i][j][r]);
        *(u16x4*)&((u16*)C)[(size_t)cn * M + rowb] = pk;   // C^T: 4 contiguous
      } else {
#pragma unroll
        for (int r = 0; r < 4; ++r)
          ((u16*)C)[(size_t)(rowb + r) * N + cn] = f2bf(acc[i][j][r]);
      }
    }
  }
}

// ---------------------------------------------------------------------------
// Split-K flash attention, S^T form, 32 q-rows/WAVE (2 strips of 16):
// 128 q-rows/block -> K/V staged once per 128 q (2x reuse vs flash5), grid
// 16x16x4 = 1024 blocks = 4/CU fully resident (no tail). FK=32 tiles,
// double-buffered global_load_lds staging, one barrier/iter, bias reg-prefetch.
// ---------------------------------------------------------------------------
#define FK 32
#define PLDV 40   // Ps row: 32 + 8 pad (80B, 16B-aligned)

__global__ __launch_bounds__(256, 4) void flash6(
    const u16* __restrict__ Q, const u16* __restrict__ Kp,
    const u16* __restrict__ Vt, const u16* __restrict__ Bb,
    u16* __restrict__ Op, float* __restrict__ lp)
{
  __shared__ __align__(16) u16 Ks[2][FK * 64];      // K-tile [l][d], swizzled
  __shared__ __align__(16) u16 Vs[2][D_HEAD * FK];  // V^T tile [d][l], swizzled
  __shared__ __align__(16) u16 Ps[4][2][16][PLDV];  // [wave][strip][q][l]

  const int h  = blockIdx.y;
  const int q0 = blockIdx.x * 128;
  const int z  = blockIdx.z;
  const int hoff = h * D_HEAD;
  const int kbase = z * (L_SEQ / KSPLIT);
  const int NT = (L_SEQ / KSPLIT) / FK;   // 16 tiles
  const int t = threadIdx.x;
  const int wave = t >> 6;
  const int lane = t & 63;
  const int quad = lane >> 4;
  const int col  = lane & 15;

  // Q fragments per strip (B-operand of S^T: n = q = col, k = d)
  bf16x8 qf[2][2];
  const u16* brow[2];
#pragma unroll
  for (int s = 0; s < 2; ++s) {
    const int qs = q0 + wave * 32 + s * 16;
    const u16* qrow = Q + (size_t)(qs + col) * E_DIM + hoff;
    qf[s][0] = *(const bf16x8*)(qrow + quad * 8);
    qf[s][1] = *(const bf16x8*)(qrow + 32 + quad * 8);
    brow[s] = Bb + (size_t)(qs + col) * L_SEQ;
  }

  // K staging: 32 rows x 8 granules; wave covers 8 rows.
  const int krow = wave * 8 + (lane >> 3);
  const int kg = ((lane & 7) ^ (lane >> 3)) * 8;
  const u16* gK = Kp + (size_t)krow * E_DIM + hoff + kg;
  // V staging: 64 rows x 4 granules; wave covers 16 rows.
  const int vrow = wave * 16 + (lane >> 2);
  const int vg = ((lane & 3) ^ ((lane >> 4) & 3)) * 8;
  const u16* gV = Vt + (size_t)(hoff + vrow) * L_SEQ + vg;

  float l_lane[2] = {0.f, 0.f};
  f32x4 oacc[2][4];
#pragma unroll
  for (int s = 0; s < 2; ++s)
#pragma unroll
    for (int td = 0; td < 4; ++td) oacc[s][td] = (f32x4){0.f, 0.f, 0.f, 0.f};

  // prologue: stage tile 0 + bias regs for tile 0
  gload16(gK + (size_t)kbase * E_DIM, &Ks[0][wave * 8 * 64]);
  gload16(gV + kbase, &Vs[0][wave * 16 * FK]);
  u16x4 bv[2][2], bn[2][2];
#pragma unroll
  for (int s = 0; s < 2; ++s) {
    bv[s][0] = *(const u16x4*)&brow[s][kbase + quad * 4];
    bv[s][1] = *(const u16x4*)&brow[s][kbase + 16 + quad * 4];
  }

  const int ks0 = (quad ^ (col & 7)) * 8;          // K frag slots (swizzled)
  const int ks1 = ((quad + 4) ^ (col & 7)) * 8;
  const int vsl = (quad ^ ((col >> 2) & 3)) * 8;   // V frag slot

  int buf = 0;
  for (int kt = 0; kt < NT; ++kt) {
    const int k0 = kbase + kt * FK;
    __syncthreads();   // tile(buf) visible; prev iter's LDS reads done
    if (kt + 1 < NT) { // prefetch next tile + next bias regs
      const int nk = k0 + FK;
      gload16(gK + (size_t)nk * E_DIM, &Ks[buf ^ 1][wave * 8 * 64]);
      gload16(gV + nk, &Vs[buf ^ 1][wave * 16 * FK]);
#pragma unroll
      for (int s = 0; s < 2; ++s) {
        bn[s][0] = *(const u16x4*)&brow[s][nk + quad * 4];
        bn[s][1] = *(const u16x4*)&brow[s][nk + 16 + quad * 4];
      }
    }
    const u16* Kb = &Ks[buf][0];
    const u16* Vb = &Vs[buf][0];

    // S^T tiles: A = K-frag (m=l), B = Q-frag (n=q); D: l=quad*4+r, q=col
#pragma unroll
    for (int tt = 0; tt < 2; ++tt) {
      const u16* kr = &Kb[(tt * 16 + col) * 64];
      bf16x8 kf0 = *(const bf16x8*)&kr[ks0];
      bf16x8 kf1 = *(const bf16x8*)&kr[ks1];
#pragma unroll
      for (int s = 0; s < 2; ++s) {
        f32x4 a = (f32x4){0.f, 0.f, 0.f, 0.f};
        a = __builtin_amdgcn_mfma_f32_16x16x32_bf16(kf0, qf[s][0], a, 0, 0, 0);
        a = __builtin_amdgcn_mfma_f32_16x16x32_bf16(kf1, qf[s][1], a, 0, 0, 0);
        float p[4];
#pragma unroll
        for (int r = 0; r < 4; ++r) {
          p[r] = __builtin_amdgcn_exp2f(fmaf(a[r], C_LOG2E_32, bf2f(bv[s][tt][r])));
          l_lane[s] += p[r];
        }
        uint2 w;
        w.x = pack_bf16_pair(p[0], p[1]);
        w.y = pack_bf16_pair(p[2], p[3]);
        *(uint2*)&Ps[wave][s][col][tt * 16 + quad * 4] = w;   // P[q=col][l..l+3]
      }
    }
    // same-wave LDS RAW (P write -> read): lgkmcnt-ordered, no barrier.

    // O += P V : A = P strip [q][l], B = V^T [d][l]
#pragma unroll
    for (int s = 0; s < 2; ++s) {
      bf16x8 pf = *(const bf16x8*)&Ps[wave][s][col][quad * 8];
#pragma unroll
      for (int td = 0; td < 4; ++td) {
        bf16x8 vf = *(const bf16x8*)&Vb[(td * 16 + col) * FK + vsl];
        oacc[s][td] = __builtin_amdgcn_mfma_f32_16x16x32_bf16(pf, vf, oacc[s][td], 0, 0, 0);
      }
    }

#pragma unroll
    for (int s = 0; s < 2; ++s) { bv[s][0] = bn[s][0]; bv[s][1] = bn[s][1]; }
    buf ^= 1;
  }

  // l reduction: lanes sharing (lane&15) hold partials across quads
#pragma unroll
  for (int s = 0; s < 2; ++s) {
    l_lane[s] += __shfl_xor(l_lane[s], 16);
    l_lane[s] += __shfl_xor(l_lane[s], 32);
    if (lane < 16)
      lp[((size_t)z * L_SEQ + q0 + wave * 32 + s * 16 + lane) * H_HEADS + h] = l_lane[s];
  }

#pragma unroll
  for (int s = 0; s < 2; ++s) {
    const int qrow_mine = q0 + wave * 32 + s * 16 + quad * 4;
#pragma unroll
    for (int td = 0; td < 4; ++td)
#pragma unroll
      for (int r = 0; r < 4; ++r)
        Op[((size_t)z * L_SEQ + qrow_mine + r) * E_DIM + hoff + td * 16 + col] = f2bf(oacc[s][td][r]);
  }
}

// ---------------------------------------------------------------------------
// Merge split-K partials: AO = (sum_s O_s) / (sum_s l_s), bf16 out.
// ---------------------------------------------------------------------------
__global__ void merge_attn(const u16* __restrict__ Op, const float* __restrict__ lp,
                           u16* __restrict__ AOb)
{
  size_t gid = (size_t)blockIdx.x * 256 + threadIdx.x;
  size_t idx = gid * 4;
  int q = (int)(idx >> 10);
  int e = (int)(idx & 1023);
  int h = e >> 6;
  float o[4] = {0.f, 0.f, 0.f, 0.f};
  float lsum = 0.f;
#pragma unroll
  for (int s = 0; s < KSPLIT; ++s) {
    u16x4 pv = *(const u16x4*)&Op[((size_t)s * L_SEQ + q) * E_DIM + e];
#pragma unroll
    for (int j = 0; j < 4; ++j) o[j] += bf2f(pv[j]);
    lsum += lp[((size_t)s * L_SEQ + q) * H_HEADS + h];
  }
  float inv = 1.f / lsum;
  u16x4 pk;
#pragma unroll
  for (int j = 0; j < 4; ++j) pk[j] = f2bf(o[j] * inv);
  *(u16x4*)&AOb[idx] = pk;
}

// ---------------------------------------------------------------------------
extern "C" void kernel_launch(void* const* d_in, const int* in_sizes, int n_in,
                              void* d_out, int out_size, void* d_ws, size_t ws_size,
                              hipStream_t stream)
{
  const float* values = (const float*)d_in[0];
  const float* keys   = (const float*)d_in[1];
  const float* query  = (const float*)d_in[2];
  const float* dist   = (const float*)d_in[3];
  const float* Wv     = (const float*)d_in[4];
  const float* Wk     = (const float*)d_in[5];
  const float* Wq     = (const float*)d_in[6];
  const float* Wo     = (const float*)d_in[7];
  const float* bo     = (const float*)d_in[8];
  float* out = (float*)d_out;

  const size_t MB = (size_t)1 << 20;
  char* w = (char*)d_ws;
  u16* xq  = (u16*)(w + 0 * MB);    // 4 MB  (dead after proj)
  u16* xk  = (u16*)(w + 4 * MB);    // 4 MB  (dead after proj)
  u16* xv  = (u16*)(w + 8 * MB);    // 4 MB  (dead after proj)
  u16* wqb = (u16*)(w + 12 * MB);   // 2 MB  (dead after proj)
  u16* wkb = (u16*)(w + 14 * MB);   // 2 MB  (dead after proj)
  u16* wvb = (u16*)(w + 16 * MB);   // 2 MB  (dead after proj)
  u16* wob = (u16*)(w + 18 * MB);   // 2 MB  (live to end)
  u16* Bb  = (u16*)(w + 20 * MB);   // 8 MB  prescaled bias bf16 [L][L]
  u16* Qh  = (u16*)(w + 28 * MB);   // 4 MB
  u16* Kh  = (u16*)(w + 32 * MB);   // 4 MB
  u16* Vth = (u16*)(w + 36 * MB);   // 4 MB  V^T [E][L]
  u16* AOb = (u16*)(w + 40 * MB);   // 4 MB
  float* lp = (float*)(w + 44 * MB);// 0.5 MB
  u16* Op  = (u16*)(w + 0 * MB);    // 16 MB, overlaps dead xq..wvb region

  // 1) convert + bias precompute + out prefill
  cvt_all<<<8192, 256, 0, stream>>>(query, keys, values, Wq, Wk, Wv, Wo, dist, bo,
                                    xq, xk, xv, wqb, wkb, wvb, wob, Bb, out);

  // 2) Q/K/V projections (z=2 -> V^T), 128x128 tiles
  dim3 gProj(E_DIM / TN, L_SEQ / TM, 3);
  gemm_pd<0><<<gProj, 256, 0, stream>>>(xq, wqb, Qh,
                                        xk, wkb, Kh,
                                        xv, wvb, Vth,
                                        L_SEQ, E_DIM, E_DIM);

  // 3) split-K flash attention, 128 q-rows/block (1024 blocks, 4/CU resident)
  dim3 gAttn(L_SEQ / 128, H_HEADS, KSPLIT);
  flash6<<<gAttn, 256, 0, stream>>>(Qh, Kh, Vth, Bb, Op, lp);

  // 4) merge partials -> bf16 AO
  merge_attn<<<(L_SEQ * E_DIM / 4) / 256, 256, 0, stream>>>(Op, lp, AOb);

  // 5) out += AO @ Wo^T, split-K=2, atomic f32 accumulate
  dim3 gOut(E_DIM / TN, L_SEQ / TM, OSPLIT);
  gemm_pd<2><<<gOut, 256, 0, stream>>>(AOb, wob, out,
                                       AOb, wob, out,
                                       AOb, wob, out,
                                       L_SEQ, E_DIM, E_DIM);
}